// Round 1
// baseline (896.145 us; speedup 1.0000x reference)
//
#include <hip/hip_runtime.h>

typedef __attribute__((ext_vector_type(8))) short short8_t;
typedef __attribute__((ext_vector_type(4))) float f32x4_t;

#define DDIM 128
#define BM   64
#define LDA  264   // ushort elems per LDS row: 528B stride -> 16B aligned, 4-bank shift/row

__device__ __forceinline__ unsigned short f2bf(float x) {
  union { float f; unsigned u; } v; v.f = x;
  unsigned r = v.u + 0x7FFFu + ((v.u >> 16) & 1u);   // RNE
  return (unsigned short)(r >> 16);
}

__device__ __forceinline__ float sigf(float x) {
  return 1.0f / (1.0f + __expf(-x));
}
__device__ __forceinline__ float tanh_fast(float x) {
  return 2.0f / (1.0f + __expf(-2.0f * x)) - 1.0f;
}

// Wt[c][k] = bf16(W[k][c]);  W:[256][640] f32, Wt:[640][256] bf16
__global__ void convert_w_kernel(const float* __restrict__ W,
                                 unsigned short* __restrict__ Wt,
                                 int twoD, int fiveD) {
  const int c = blockIdx.x;    // 0..fiveD-1
  const int k = threadIdx.x;   // 0..twoD-1
  Wt[c * twoD + k] = f2bf(W[k * fiveD + c]);
}

__global__ __launch_bounds__(512)
void treelstm_fused_kernel(const float* __restrict__ h_bot,
                           const float* __restrict__ c_bot,
                           const float* __restrict__ h_buf,
                           const float* __restrict__ c_buf,
                           const int* __restrict__ idx_bl,
                           const int* __restrict__ idx_pl,
                           const int* __restrict__ idx_br,
                           const int* __restrict__ idx_pr,
                           const float* __restrict__ bias,
                           const unsigned short* __restrict__ Wt,
                           float* __restrict__ out,
                           int K, int M) {
  __shared__ __align__(16) unsigned short A_lds[BM * LDA];

  const int tid   = threadIdx.x;
  const int mbase = blockIdx.x * BM;

  // ---- stage gathered h rows -> LDS bf16  (A[m][0:128]=h_l, A[m][128:256]=h_r) ----
  {
    const int r    = tid >> 3;        // 0..63 local row
    const int seg  = tid & 7;         // 8 threads per row
    const int half = seg >> 2;        // 0: left (h_l), 1: right (h_r)
    const int cs   = seg & 3;         // 4 threads per half
    const int m    = mbase + r;

    unsigned short* dst = &A_lds[r * LDA + half * DDIM];
    if (m < M) {
      int idx;
      const float* base;
      if (half == 0) {
        if (m < K) { idx = idx_bl[m];     base = h_bot; }
        else       { idx = idx_pl[m - K]; base = h_buf; }
      } else {
        if (m < K) { idx = idx_br[m];     base = h_bot; }
        else       { idx = idx_pr[m - K]; base = h_buf; }
      }
      const float4* s4 = (const float4*)(base + (size_t)idx * DDIM);
      #pragma unroll
      for (int q = 0; q < 8; ++q) {
        const int f4i = cs + 4 * q;            // 0..31 within the half
        float4 v = s4[f4i];
        ushort4 w;
        w.x = f2bf(v.x); w.y = f2bf(v.y); w.z = f2bf(v.z); w.w = f2bf(v.w);
        *(ushort4*)(dst + f4i * 4) = w;
      }
    } else {
      #pragma unroll
      for (int q = 0; q < 8; ++q) {
        const int f4i = cs + 4 * q;
        ushort4 w; w.x = w.y = w.z = w.w = 0;
        *(ushort4*)(dst + f4i * 4) = w;
      }
    }
  }
  __syncthreads();

  // ---- GEMM: per wave, one 16-wide d-block x 5 gates x 4 row-tiles ----
  const int wave = tid >> 6;          // 0..7  -> d-block
  const int lane = tid & 63;
  const int l16  = lane & 15;
  const int lq   = lane >> 4;         // 0..3

  f32x4_t acc[4][5];
  #pragma unroll
  for (int rt = 0; rt < 4; ++rt)
    #pragma unroll
    for (int g = 0; g < 5; ++g) {
      f32x4_t z = {0.0f, 0.0f, 0.0f, 0.0f};
      acc[rt][g] = z;
    }

  // B fragment base: col = g*128 + wave*16 + l16 ; elems along k contiguous
  const unsigned short* wbase = Wt + ((wave * 16 + l16) * 256 + lq * 8);
  const int abase = l16 * LDA + lq * 8;

  #pragma unroll
  for (int kk = 0; kk < 8; ++kk) {
    const int k0 = kk * 32;
    short8_t afrag[4];
    #pragma unroll
    for (int rt = 0; rt < 4; ++rt)
      afrag[rt] = *(const short8_t*)(&A_lds[abase + rt * (16 * LDA) + k0]);

    #pragma unroll
    for (int g = 0; g < 5; ++g) {
      short8_t bfrag = *(const short8_t*)(wbase + g * (128 * 256) + k0);
      #pragma unroll
      for (int rt = 0; rt < 4; ++rt)
        acc[rt][g] = __builtin_amdgcn_mfma_f32_16x16x32_bf16(
            afrag[rt], bfrag, acc[rt][g], 0, 0, 0);
    }
  }

  // ---- epilogue: gates + c-gather + LSTM cell, register-local per lane ----
  const int d = wave * 16 + l16;
  const float bi  = bias[0 * DDIM + d];
  const float bo  = bias[1 * DDIM + d];
  const float bu  = bias[2 * DDIM + d];
  const float bfl = bias[3 * DDIM + d];
  const float bfr = bias[4 * DDIM + d];

  float* __restrict__ out_h = out;
  float* __restrict__ out_c = out + (size_t)M * DDIM;

  #pragma unroll
  for (int rt = 0; rt < 4; ++rt) {
    #pragma unroll
    for (int j = 0; j < 4; ++j) {
      const int m = mbase + rt * 16 + lq * 4 + j;
      if (m >= M) continue;
      const float gi = acc[rt][0][j] + bi;
      const float go = acc[rt][1][j] + bo;
      const float gu = acc[rt][2][j] + bu;
      const float gl = acc[rt][3][j] + bfl;
      const float gr = acc[rt][4][j] + bfr;

      float clv, crv;
      if (m < K) clv = c_bot[(size_t)idx_bl[m] * DDIM + d];
      else       clv = c_buf[(size_t)idx_pl[m - K] * DDIM + d];
      if (m < K) crv = c_bot[(size_t)idx_br[m] * DDIM + d];
      else       crv = c_buf[(size_t)idx_pr[m - K] * DDIM + d];

      const float cn = sigf(gi) * tanh_fast(gu) + sigf(gl) * clv + sigf(gr) * crv;
      const float hn = sigf(go) * tanh_fast(cn);
      out_h[(size_t)m * DDIM + d] = hn;
      out_c[(size_t)m * DDIM + d] = cn;
    }
  }
}

extern "C" void kernel_launch(void* const* d_in, const int* in_sizes, int n_in,
                              void* d_out, int out_size, void* d_ws, size_t ws_size,
                              hipStream_t stream) {
  const float* h_bot  = (const float*)d_in[0];
  const float* c_bot  = (const float*)d_in[1];
  const float* h_buf  = (const float*)d_in[2];
  const float* c_buf  = (const float*)d_in[3];
  const int*   idx_bl = (const int*)d_in[4];
  const int*   idx_pl = (const int*)d_in[5];
  const int*   idx_br = (const int*)d_in[6];
  const int*   idx_pr = (const int*)d_in[7];
  const float* W      = (const float*)d_in[8];
  const float* bias   = (const float*)d_in[9];

  const int K = in_sizes[4];
  const int M = 2 * K;
  const int fiveD = in_sizes[9];               // 640
  const int twoD  = in_sizes[8] / fiveD;       // 256

  unsigned short* Wt = (unsigned short*)d_ws;  // [640][256] bf16 = 320 KB

  hipLaunchKernelGGL(convert_w_kernel, dim3(fiveD), dim3(twoD), 0, stream,
                     W, Wt, twoD, fiveD);

  const int grid = (M + BM - 1) / BM;
  hipLaunchKernelGGL(treelstm_fused_kernel, dim3(grid), dim3(512), 0, stream,
                     h_bot, c_bot, h_buf, c_buf,
                     idx_bl, idx_pl, idx_br, idx_pr,
                     bias, Wt, (float*)d_out, K, M);
}

// Round 2
// 536.878 us; speedup vs baseline: 1.6692x; 1.6692x over previous
//
#include <hip/hip_runtime.h>

typedef __attribute__((ext_vector_type(8))) short short8_t;
typedef __attribute__((ext_vector_type(4))) float f32x4_t;

#define DDIM 128
#define BM   64
#define LDA  264   // ushort elems per LDS row: 528B stride, 16B aligned, 4-bank shift/row

__device__ __forceinline__ unsigned short f2bf(float x) {
  union { float f; unsigned u; } v; v.f = x;
  unsigned r = v.u + 0x7FFFu + ((v.u >> 16) & 1u);   // RNE
  return (unsigned short)(r >> 16);
}

__device__ __forceinline__ float sigf(float x) {
  return 1.0f / (1.0f + __expf(-x));
}
__device__ __forceinline__ float tanh_fast(float x) {
  return 2.0f / (1.0f + __expf(-2.0f * x)) - 1.0f;
}

// Wt[c][k] = bf16(W[k][c]);  W:[256][640] f32, Wt:[640][256] bf16
__global__ void convert_w_kernel(const float* __restrict__ W,
                                 unsigned short* __restrict__ Wt,
                                 int twoD, int fiveD) {
  const int c = blockIdx.x;    // 0..fiveD-1
  const int k = threadIdx.x;   // 0..twoD-1
  Wt[c * twoD + k] = f2bf(W[k * fiveD + c]);
}

__global__ __launch_bounds__(512)
void treelstm_fused_kernel(const float* __restrict__ h_bot,
                           const float* __restrict__ c_bot,
                           const float* __restrict__ h_buf,
                           const float* __restrict__ c_buf,
                           const int* __restrict__ idx_bl,
                           const int* __restrict__ idx_pl,
                           const int* __restrict__ idx_br,
                           const int* __restrict__ idx_pr,
                           const float* __restrict__ bias,
                           const unsigned short* __restrict__ Wt,
                           float* __restrict__ out,
                           int K, int M) {
  __shared__ __align__(16) unsigned short A_lds[BM * LDA];

  const int tid   = threadIdx.x;
  const int mbase = blockIdx.x * BM;
  if (mbase >= M) return;

  const int wave = tid >> 6;          // 0..7 -> dt (16-wide d-block)
  const int lane = tid & 63;
  const int l16  = lane & 15;
  const int lq   = lane >> 4;         // 0..3
  const int d0   = wave * 16 + lq * 4;

  // ---- issue gathered h row loads (f32) ----
  const int r    = tid >> 3;          // 0..63 local row
  const int seg  = tid & 7;
  const int half = seg >> 2;          // 0: h_l, 1: h_r
  const int cs   = seg & 3;
  const int ms   = mbase + r;

  float4 hv[8];
  {
    int hidx; const float* hsrc;
    if (half == 0) {
      if (ms < K) { hidx = idx_bl[ms];     hsrc = h_bot; }
      else        { hidx = idx_pl[ms - K]; hsrc = h_buf; }
    } else {
      if (ms < K) { hidx = idx_br[ms];     hsrc = h_bot; }
      else        { hidx = idx_pr[ms - K]; hsrc = h_buf; }
    }
    const float4* s4 = (const float4*)(hsrc + (size_t)hidx * DDIM);
    #pragma unroll
    for (int q = 0; q < 8; ++q) hv[q] = s4[cs + 4 * q];
  }

  // ---- prefetch epilogue operands (idx -> c float4 gathers, bias) ----
  f32x4_t cl[4], cr[4], bs[5];
  int mvec[4];
  #pragma unroll
  for (int mt = 0; mt < 4; ++mt) {
    const int m = mbase + mt * 16 + l16;
    mvec[mt] = m;
    int il, ir; const float *cls, *crs;
    if (m < K) { il = idx_bl[m];     cls = c_bot; }
    else       { il = idx_pl[m - K]; cls = c_buf; }
    if (m < K) { ir = idx_br[m];     crs = c_bot; }
    else       { ir = idx_pr[m - K]; crs = c_buf; }
    cl[mt] = *(const f32x4_t*)(cls + (size_t)il * DDIM + d0);
    cr[mt] = *(const f32x4_t*)(crs + (size_t)ir * DDIM + d0);
  }
  #pragma unroll
  for (int g = 0; g < 5; ++g)
    bs[g] = *(const f32x4_t*)(bias + g * DDIM + d0);

  // ---- convert + write staged h to LDS (bf16) ----
  {
    unsigned short* dst = &A_lds[r * LDA + half * DDIM];
    #pragma unroll
    for (int q = 0; q < 8; ++q) {
      ushort4 w;
      w.x = f2bf(hv[q].x); w.y = f2bf(hv[q].y);
      w.z = f2bf(hv[q].z); w.w = f2bf(hv[q].w);
      *(ushort4*)(dst + (cs + 4 * q) * 4) = w;
    }
  }
  __syncthreads();

  // ---- GEMM: D[d][m] = sum_k Wt[d'][k] * h[m][k]  (W as A-operand, h as B) ----
  f32x4_t acc[4][5];
  #pragma unroll
  for (int mt = 0; mt < 4; ++mt)
    #pragma unroll
    for (int g = 0; g < 5; ++g) {
      f32x4_t z = {0.0f, 0.0f, 0.0f, 0.0f};
      acc[mt][g] = z;
    }

  const unsigned short* wb = Wt + (size_t)(wave * 16 + l16) * 256 + lq * 8;
  const int ab = l16 * LDA + lq * 8;

  #pragma unroll
  for (int kk = 0; kk < 8; ++kk) {
    const int k0 = kk * 32;
    short8_t wf[5];
    #pragma unroll
    for (int g = 0; g < 5; ++g)
      wf[g] = *(const short8_t*)(wb + (size_t)g * (128 * 256) + k0);
    short8_t hf[4];
    #pragma unroll
    for (int mt = 0; mt < 4; ++mt)
      hf[mt] = *(const short8_t*)(&A_lds[ab + mt * (16 * LDA) + k0]);
    #pragma unroll
    for (int g = 0; g < 5; ++g)
      #pragma unroll
      for (int mt = 0; mt < 4; ++mt)
        acc[mt][g] = __builtin_amdgcn_mfma_f32_16x16x32_bf16(
            wf[g], hf[mt], acc[mt][g], 0, 0, 0);
  }

  // ---- epilogue: lane owns 4 consecutive d's at one m -> float4 I/O ----
  float* __restrict__ out_h = out;
  float* __restrict__ out_c = out + (size_t)M * DDIM;

  #pragma unroll
  for (int mt = 0; mt < 4; ++mt) {
    f32x4_t hv4, cv4;
    #pragma unroll
    for (int j = 0; j < 4; ++j) {
      const float gi = acc[mt][0][j] + bs[0][j];
      const float go = acc[mt][1][j] + bs[1][j];
      const float gu = acc[mt][2][j] + bs[2][j];
      const float gl = acc[mt][3][j] + bs[3][j];
      const float gr = acc[mt][4][j] + bs[4][j];
      const float cn = sigf(gi) * tanh_fast(gu)
                     + sigf(gl) * cl[mt][j] + sigf(gr) * cr[mt][j];
      const float hn = sigf(go) * tanh_fast(cn);
      cv4[j] = cn; hv4[j] = hn;
    }
    const size_t off = (size_t)mvec[mt] * DDIM + d0;
    *(f32x4_t*)(out_h + off) = hv4;
    *(f32x4_t*)(out_c + off) = cv4;
  }
}

extern "C" void kernel_launch(void* const* d_in, const int* in_sizes, int n_in,
                              void* d_out, int out_size, void* d_ws, size_t ws_size,
                              hipStream_t stream) {
  const float* h_bot  = (const float*)d_in[0];
  const float* c_bot  = (const float*)d_in[1];
  const float* h_buf  = (const float*)d_in[2];
  const float* c_buf  = (const float*)d_in[3];
  const int*   idx_bl = (const int*)d_in[4];
  const int*   idx_pl = (const int*)d_in[5];
  const int*   idx_br = (const int*)d_in[6];
  const int*   idx_pr = (const int*)d_in[7];
  const float* W      = (const float*)d_in[8];
  const float* bias   = (const float*)d_in[9];

  const int K = in_sizes[4];
  const int M = 2 * K;
  const int fiveD = in_sizes[9];               // 640
  const int twoD  = in_sizes[8] / fiveD;       // 256

  unsigned short* Wt = (unsigned short*)d_ws;  // [640][256] bf16 = 320 KB

  hipLaunchKernelGGL(convert_w_kernel, dim3(fiveD), dim3(twoD), 0, stream,
                     W, Wt, twoD, fiveD);

  const int grid = (M + BM - 1) / BM;
  hipLaunchKernelGGL(treelstm_fused_kernel, dim3(grid), dim3(512), 0, stream,
                     h_bot, c_bot, h_buf, c_buf,
                     idx_bl, idx_pl, idx_br, idx_pr,
                     bias, Wt, (float*)d_out, K, M);
}